// Round 19
// baseline (179.917 us; speedup 1.0000x reference)
//
#include <hip/hip_runtime.h>

#define GRID 64
#define NVOX (GRID*GRID*GRID)
#define NCLS 20
#define NSEED 512

typedef __attribute__((ext_vector_type(8))) short short8_t;
typedef __attribute__((ext_vector_type(4))) float float4_t;

__device__ __forceinline__ unsigned short f32_to_bf16_rne(float f) {
    unsigned int x = __float_as_uint(f);
    unsigned int r = (x + 0x7fffu + ((x >> 16) & 1u)) >> 16;
    return (unsigned short)r;
}
__device__ __forceinline__ float bf16_to_f32(unsigned short u) {
    return __uint_as_float(((unsigned int)u) << 16);
}

// ------- w1 transpose + seed table prep -------
__global__ void transpose_w1(const float* __restrict__ w1, float* __restrict__ w1t,
                             const float* __restrict__ ann, float* __restrict__ seedtab,
                             int* __restrict__ slabtab) {
    int t = blockIdx.x * 256 + threadIdx.x;
    if (t < 27 * 6 * 64) {
        int oc = t & 63;
        int r  = t >> 6;            // nb*6 + ci
        int nb = r / 6, ci = r % 6;
        w1t[t] = w1[oc * 162 + ci * 27 + nb];
        return;
    }
    int i = t - 27 * 6 * 64;
    if (i < NSEED) {
        float a0 = ann[i*4+0], a1 = ann[i*4+1], a2 = ann[i*4+2];
        *reinterpret_cast<float4*>(seedtab + i * 4) =
            make_float4(a0, a1, a2, a0*a0 + a1*a1 + a2*a2);
        slabtab[i] = (int)ann[i*4+3];
    }
}

// ------- build conv2 weight MFMA fragments (bf16 hi only), 108 frags x 1KB -------
// frag f = (nb*2+s)*2+t ; lane l elem j: B[ci=s*32+(l>>4)*8+j][oc=t*16+(l&15)]
__global__ void build_bfrags(const float* __restrict__ w2, unsigned short* __restrict__ bfr) {
    int t = blockIdx.x * 256 + threadIdx.x;      // over 108*64
    if (t >= 108 * 64) return;
    int l  = t & 63;
    int f  = t >> 6;
    int tt = f & 1;
    int s  = (f >> 1) & 1;
    int nb = f >> 2;
    int lr = l & 15, lg = l >> 4;
    int oc = tt * 16 + lr;
    short8_t out;
    #pragma unroll
    for (int j = 0; j < 8; ++j) {
        int ci = s * 32 + lg * 8 + j;
        out[j] = (short)f32_to_bf16_rne(w2[oc * 1728 + ci * 27 + nb]);
    }
    *reinterpret_cast<short8_t*>(bfr + f * 512 + l * 8) = out;
}

// ------- conv1 (6->64): Zd=4, oc=16, all-tap LDS weights; 9-tap FULL UNROLL (masked) -------
// h1 frag layout per (z,y) plane (4096 elems): [xt(4)][s(2)][cc(4)][xl(16)][8ci]
__global__ __launch_bounds__(256, 4) void conv1_kernel(
    const float* __restrict__ feat,   // [6][NVOX]
    const float* __restrict__ w1t,    // [(nb*6+ci)][64]
    const float* __restrict__ b1,
    unsigned short* __restrict__ h1hi)
{
    __shared__ float lw[27 * 6 * 16]; // 10368 B

    int tid = threadIdx.x;
    int B = blockIdx.x;
    int zg = B & 7;
    int k  = B >> 3;
    int og = k & 3;                   // oc group of 16
    int zt = (k >> 2) & 1;
    int yt = (k >> 3) & 15;

    for (int t = tid; t < 27 * 6 * 16; t += 256)
        lw[t] = w1t[(t >> 4) * 64 + og * 16 + (t & 15)];
    __syncthreads();                  // the only barrier

    int x  = tid & 63;
    int y  = yt * 4 + (tid >> 6);     // wave-uniform
    int z0 = zg * 8 + zt * 4;

    float acc[4][16];
    #pragma unroll
    for (int r = 0; r < 4; ++r)
        #pragma unroll
        for (int o = 0; o < 16; ++o) acc[r][o] = 0.f;

    int zoffv[6]; float mzv[6];
    #pragma unroll
    for (int rz = 0; rz < 6; ++rz) {
        int gz = z0 - 1 + rz;
        int cz = gz < 0 ? 0 : (gz > 63 ? 63 : gz);
        zoffv[rz] = cz * 4096;
        mzv[rz] = ((unsigned)gz < 64u) ? 1.f : 0.f;
    }

    // FULL unroll: masked edges (no branches) -> compiler pipelines loads across taps
    #pragma unroll
    for (int dydx = 0; dydx < 9; ++dydx) {
        int dy = dydx / 3 - 1;
        int dx = dydx % 3 - 1;
        int ny = y + dy;
        float my = ((unsigned)ny < 64u) ? 1.f : 0.f;
        int cy = ny < 0 ? 0 : (ny > 63 ? 63 : ny);
        int nx = x + dx;
        float mxv = ((unsigned)nx < 64u) ? 1.f : 0.f;
        int cx = nx < 0 ? 0 : (nx > 63 ? 63 : nx);
        int rowvox = cy * 64 + cx;
        float mxy = mxv * my;

        float cm[6]; int voff[6];
        #pragma unroll
        for (int rz = 0; rz < 6; ++rz) { cm[rz] = mxy * mzv[rz]; voff[rz] = zoffv[rz] + rowvox; }

        #pragma unroll
        for (int cb = 0; cb < 2; ++cb) {
            float v[3][6];
            #pragma unroll
            for (int ci = 0; ci < 3; ++ci) {
                const float* plane = feat + (size_t)(cb * 3 + ci) * NVOX;
                #pragma unroll
                for (int rz = 0; rz < 6; ++rz) v[ci][rz] = plane[voff[rz]];
            }
            #pragma unroll
            for (int ci = 0; ci < 3; ++ci)
                #pragma unroll
                for (int rz = 0; rz < 6; ++rz) v[ci][rz] *= cm[rz];
            #pragma unroll
            for (int ci = 0; ci < 3; ++ci) {
                #pragma unroll
                for (int dzi = 0; dzi < 3; ++dzi) {
                    const float4* wp = reinterpret_cast<const float4*>(
                        &lw[(((dzi * 9 + dydx) * 6) + cb * 3 + ci) * 16]);
                    float4 w0 = wp[0], w1 = wp[1], w2 = wp[2], w3 = wp[3];
                    #pragma unroll
                    for (int r = 0; r < 4; ++r) {
                        float a = v[ci][r + dzi];
                        acc[r][0]  = fmaf(a, w0.x, acc[r][0]);
                        acc[r][1]  = fmaf(a, w0.y, acc[r][1]);
                        acc[r][2]  = fmaf(a, w0.z, acc[r][2]);
                        acc[r][3]  = fmaf(a, w0.w, acc[r][3]);
                        acc[r][4]  = fmaf(a, w1.x, acc[r][4]);
                        acc[r][5]  = fmaf(a, w1.y, acc[r][5]);
                        acc[r][6]  = fmaf(a, w1.z, acc[r][6]);
                        acc[r][7]  = fmaf(a, w1.w, acc[r][7]);
                        acc[r][8]  = fmaf(a, w2.x, acc[r][8]);
                        acc[r][9]  = fmaf(a, w2.y, acc[r][9]);
                        acc[r][10] = fmaf(a, w2.z, acc[r][10]);
                        acc[r][11] = fmaf(a, w2.w, acc[r][11]);
                        acc[r][12] = fmaf(a, w3.x, acc[r][12]);
                        acc[r][13] = fmaf(a, w3.y, acc[r][13]);
                        acc[r][14] = fmaf(a, w3.z, acc[r][14]);
                        acc[r][15] = fmaf(a, w3.w, acc[r][15]);
                    }
                }
            }
        }
    }

    float bias[16];
    #pragma unroll
    for (int o = 0; o < 16; ++o) bias[o] = b1[og * 16 + o];

    // frag-layout store (hi only): s = og>>1; cc = (og*2 + (o>>3)) & 3
    int s1 = og >> 1;
    int c0 = (og * 2) & 3;
    int c1 = (og * 2 + 1) & 3;
    #pragma unroll
    for (int zl = 0; zl < 4; ++zl) {
        size_t zy = ((size_t)((z0 + zl) * 64 + y)) * 4096;
        size_t base  = zy + (size_t)(x >> 4) * 1024 + (size_t)s1 * 512 + (size_t)(x & 15) * 8;
        short8_t hi0, hi1;
        #pragma unroll
        for (int o = 0; o < 8; ++o)
            hi0[o] = (short)f32_to_bf16_rne(fmaxf(acc[zl][o] + bias[o], 0.f));
        #pragma unroll
        for (int o = 8; o < 16; ++o)
            hi1[o - 8] = (short)f32_to_bf16_rne(fmaxf(acc[zl][o] + bias[o], 0.f));
        *reinterpret_cast<short8_t*>(h1hi + base + c0 * 128) = hi0;
        *reinterpret_cast<short8_t*>(h1hi + base + c1 * 128) = hi1;
    }
}

// ------- conv2 (64->32) MFMA + fused epilogue; one-row-ahead A prefetch; zl-fast dispatch -------
// grid 1024 = 8 zg (XCD, fastest) x 8 zl x 16 yt (slowest); z-adjacent blocks launch-adjacent.
__global__ __launch_bounds__(256, 4) void conv2_fused_kernel(
    const unsigned short* __restrict__ h1hi, // frag layout
    const unsigned short* __restrict__ bfr,  // [27][2s][2t][64][8] bf16 (hi only)
    const float* __restrict__ b2,
    const float* __restrict__ seedtab,       // [512][4] (x,y,z,|s|^2)
    const int* __restrict__ slabtab,         // [512]
    const float* __restrict__ points,
    const float* __restrict__ sem_w, const float* __restrict__ sem_b,
    const float* __restrict__ off_w, const float* __restrict__ off_b,
    float* __restrict__ out_logits,
    float* __restrict__ out_off,
    int* __restrict__ iv_out,
    unsigned* __restrict__ bitmapT)          // [16 words][1024 blocks]
{
    __shared__ unsigned short smem[4 * 4096]; // per-wave A-row staging; reused as pf store. 32 KB
    __shared__ int lbad[NSEED];               // 2048 B  (total 34 KB -> 4 blocks/CU)

    int tid = threadIdx.x;
    lbad[tid] = 0;
    lbad[tid + 256] = 0;

    int w   = tid >> 6;
    int l   = tid & 63;
    int B   = blockIdx.x;
    int zg  = B & 7;
    int zl  = (B >> 3) & 7;           // fast -> z-neighbors adjacent in dispatch
    int yt  = B >> 6;                 // slowest
    int z   = zg * 8 + zl;
    int y   = yt * 4 + w;             // wave-uniform

    int lr = l & 15;
    int lg = l >> 4;

    unsigned short* wsh = &smem[w * 4096];    // this wave's private region

    // per-lane LDS read offsets for shifted fragments: dxs=0 -> dx=-1, dxs=1 -> dx=+1
    int loff[4][2]; bool lok[4][2];
    #pragma unroll
    for (int vt = 0; vt < 4; ++vt) {
        #pragma unroll
        for (int dxs = 0; dxs < 2; ++dxs) {
            int v = vt * 16 + lr + (dxs ? 1 : -1);
            lok[vt][dxs] = (unsigned)v < 64u;
            int vc = v < 0 ? 0 : (v > 63 ? 63 : v);
            loff[vt][dxs] = (vc >> 4) * 1024 + lg * 128 + (vc & 15) * 8;
        }
    }

    // row clamps + validity (block/wave-uniform)
    int czv[3]; bool zokv[3];
    #pragma unroll
    for (int dzi = 0; dzi < 3; ++dzi) {
        int nz = z + dzi - 1;
        zokv[dzi] = (unsigned)nz < 64u;
        czv[dzi] = nz < 0 ? 0 : (nz > 63 ? 63 : nz);
    }
    int cyv[3]; bool yokv[3];
    #pragma unroll
    for (int dyi = 0; dyi < 3; ++dyi) {
        int ny = y + dyi - 1;
        yokv[dyi] = (unsigned)ny < 64u;
        cyv[dyi] = ny < 0 ? 0 : (ny > 63 ? 63 : ny);
    }

    const unsigned short* phv[9]; bool rvv[9];
    #pragma unroll
    for (int rp = 0; rp < 9; ++rp) {
        int dzi = rp / 3, dyi = rp % 3;
        rvv[rp] = zokv[dzi] && yokv[dyi];
        phv[rp] = h1hi + (size_t)(czv[dzi] * 64 + cyv[dyi]) * 4096;
    }

    const short8_t zero8 = (short8_t)0;
    float4_t acc[4][2];
    #pragma unroll
    for (int a = 0; a < 4; ++a)
        #pragma unroll
        for (int b = 0; b < 2; ++b) acc[a][b] = (float4_t)0.f;

    // one-row-ahead software prefetch (all-static double buffer; straight-line code)
    short8_t pre[2][4][2];
    #pragma unroll
    for (int vt = 0; vt < 4; ++vt)
        #pragma unroll
        for (int s = 0; s < 2; ++s) {
            short8_t t8 = *reinterpret_cast<const short8_t*>(phv[0] + vt * 1024 + s * 512 + l * 8);
            pre[0][vt][s] = rvv[0] ? t8 : zero8;
        }

    #pragma unroll
    for (int rp = 0; rp < 9; ++rp) {
        int cur = rp & 1, nxt = cur ^ 1;
        if (rp < 8) {                         // issue next row's loads before current row's compute
            #pragma unroll
            for (int vt = 0; vt < 4; ++vt)
                #pragma unroll
                for (int s = 0; s < 2; ++s) {
                    short8_t t8 = *reinterpret_cast<const short8_t*>(phv[rp + 1] + vt * 1024 + s * 512 + l * 8);
                    pre[nxt][vt][s] = rvv[rp + 1] ? t8 : zero8;
                }
        }
        // stage current row into wave-private LDS (in-order lgkm handles RAW/WAR)
        #pragma unroll
        for (int vt = 0; vt < 4; ++vt)
            #pragma unroll
            for (int s = 0; s < 2; ++s)
                *reinterpret_cast<short8_t*>(wsh + vt * 1024 + s * 512 + l * 8) = pre[cur][vt][s];

        int dzi = rp / 3, dyi = rp % 3;
        #pragma unroll
        for (int dxm = 0; dxm < 3; ++dxm) {   // compile-time (rule #20)
            int nb = dzi * 9 + dyi * 3 + dxm;
            const unsigned short* bt = bfr + nb * 2048 + l * 8;
            #pragma unroll
            for (int s = 0; s < 2; ++s) {
                const unsigned short* bs = bt + s * 1024;
                short8_t bh0 = *reinterpret_cast<const short8_t*>(bs);
                short8_t bh1 = *reinterpret_cast<const short8_t*>(bs + 512);

                short8_t a0, a1, a2, a3;
                if (dxm == 1) {
                    a0 = pre[cur][0][s]; a1 = pre[cur][1][s]; a2 = pre[cur][2][s]; a3 = pre[cur][3][s];
                } else {
                    int dxs = (dxm == 2) ? 1 : 0;
                    a0 = lok[0][dxs] ? *reinterpret_cast<const short8_t*>(wsh + loff[0][dxs] + s * 512) : zero8;
                    a1 = lok[1][dxs] ? *reinterpret_cast<const short8_t*>(wsh + loff[1][dxs] + s * 512) : zero8;
                    a2 = lok[2][dxs] ? *reinterpret_cast<const short8_t*>(wsh + loff[2][dxs] + s * 512) : zero8;
                    a3 = lok[3][dxs] ? *reinterpret_cast<const short8_t*>(wsh + loff[3][dxs] + s * 512) : zero8;
                }

                acc[0][0] = __builtin_amdgcn_mfma_f32_16x16x32_bf16(a0, bh0, acc[0][0], 0, 0, 0);
                acc[0][1] = __builtin_amdgcn_mfma_f32_16x16x32_bf16(a0, bh1, acc[0][1], 0, 0, 0);
                acc[1][0] = __builtin_amdgcn_mfma_f32_16x16x32_bf16(a1, bh0, acc[1][0], 0, 0, 0);
                acc[1][1] = __builtin_amdgcn_mfma_f32_16x16x32_bf16(a1, bh1, acc[1][1], 0, 0, 0);
                acc[2][0] = __builtin_amdgcn_mfma_f32_16x16x32_bf16(a2, bh0, acc[2][0], 0, 0, 0);
                acc[2][1] = __builtin_amdgcn_mfma_f32_16x16x32_bf16(a2, bh1, acc[2][1], 0, 0, 0);
                acc[3][0] = __builtin_amdgcn_mfma_f32_16x16x32_bf16(a3, bh0, acc[3][0], 0, 0, 0);
                acc[3][1] = __builtin_amdgcn_mfma_f32_16x16x32_bf16(a3, bh1, acc[3][1], 0, 0, 0);
            }
        }
    }

    // ---- bias + relu -> per-wave pf region (bf16, stride 40; region private to this wave) ----
    #pragma unroll
    for (int vt = 0; vt < 4; ++vt) {
        #pragma unroll
        for (int t = 0; t < 2; ++t) {
            float bias = b2[t * 16 + lr];
            #pragma unroll
            for (int r = 0; r < 4; ++r) {
                int vl = vt * 16 + lg * 4 + r;            // voxel within this wave's row
                wsh[vl * 40 + t * 16 + lr] = f32_to_bf16_rne(fmaxf(acc[vt][t][r] + bias, 0.f));
            }
        }
    }
    __syncthreads();   // publishes lbad zero-init (pf stays wave-private)

    // ---- per-thread epilogue: voxel = (z, y of own wave, x = lane) ----
    int ex = tid & 63, ey = yt * 4 + (tid >> 6);
    int vox = (z * 64 + ey) * 64 + ex;

    float f[32];
    #pragma unroll
    for (int q = 0; q < 4; ++q) {
        short8_t v8 = *reinterpret_cast<const short8_t*>(&wsh[(tid & 63) * 40 + q * 8]);
        #pragma unroll
        for (int kk = 0; kk < 8; ++kk) f[q*8+kk] = bf16_to_f32((unsigned short)v8[kk]);
    }

    // semantic head + argmax (wave-uniform weight indices -> s_load; strict > = first occurrence)
    float lbuf[20];
    float best = -1e30f; int am = 0;
    #pragma unroll
    for (int cc = 0; cc < NCLS; ++cc) {
        float a = sem_b[cc];
        #pragma unroll
        for (int q = 0; q < 32; ++q) a = fmaf(f[q], sem_w[cc * 32 + q], a);
        lbuf[cc] = a;
        if (a > best) { best = a; am = cc; }
    }
    #pragma unroll
    for (int q5 = 0; q5 < 5; ++q5)
        *reinterpret_cast<float4*>(out_logits + (size_t)vox * NCLS + q5 * 4) =
            make_float4(lbuf[q5*4], lbuf[q5*4+1], lbuf[q5*4+2], lbuf[q5*4+3]);

    // offset head
    float off[3];
    #pragma unroll
    for (int k3 = 0; k3 < 3; ++k3) {
        float a = off_b[k3];
        #pragma unroll
        for (int q = 0; q < 32; ++q) a = fmaf(f[q], off_w[k3 * 32 + q], a);
        out_off[(size_t)vox * 3 + k3] = a;
        off[k3] = a;
    }

    float px = points[(size_t)vox * 3 + 0] + off[0];
    float py = points[(size_t)vox * 3 + 1] + off[1];
    float pz = points[(size_t)vox * 3 + 2] + off[2];
    float c  = px*px + py*py + pz*pz;
    float mx = -2.f*px, my = -2.f*py, mz = -2.f*pz;

    // seed scan: 4 interleaved chains (ILP on the min dependency), s_load seeds
    float bd0 = 1e30f, bd1 = 1e30f, bd2 = 1e30f, bd3 = 1e30f;
    int   bj0 = 0,     bj1 = 0,     bj2 = 0,     bj3 = 0;
    #pragma unroll 2
    for (int j = 0; j < NSEED; j += 4) {
        float4 s0 = *reinterpret_cast<const float4*>(seedtab + (j + 0) * 4);
        float4 s1 = *reinterpret_cast<const float4*>(seedtab + (j + 1) * 4);
        float4 s2 = *reinterpret_cast<const float4*>(seedtab + (j + 2) * 4);
        float4 s3 = *reinterpret_cast<const float4*>(seedtab + (j + 3) * 4);
        float d0 = fmaf(mx, s0.x, fmaf(my, s0.y, fmaf(mz, s0.z, c + s0.w)));
        float d1 = fmaf(mx, s1.x, fmaf(my, s1.y, fmaf(mz, s1.z, c + s1.w)));
        float d2 = fmaf(mx, s2.x, fmaf(my, s2.y, fmaf(mz, s2.z, c + s2.w)));
        float d3 = fmaf(mx, s3.x, fmaf(my, s3.y, fmaf(mz, s3.z, c + s3.w)));
        if (d0 < bd0) { bd0 = d0; bj0 = j; }          // strict < per chain
        if (d1 < bd1) { bd1 = d1; bj1 = j + 1; }
        if (d2 < bd2) { bd2 = d2; bj2 = j + 2; }
        if (d3 < bd3) { bd3 = d3; bj3 = j + 3; }
    }
    // merge with index tie-break -> global first occurrence
    bool p01 = (bd0 < bd1) || (bd0 == bd1 && bj0 < bj1);
    float bdA = p01 ? bd0 : bd1; int bjA = p01 ? bj0 : bj1;
    bool p23 = (bd2 < bd3) || (bd2 == bd3 && bj2 < bj3);
    float bdB = p23 ? bd2 : bd3; int bjB = p23 ? bj2 : bj3;
    bool pAB = (bdA < bdB) || (bdA == bdB && bjA < bjB);
    float bd = pAB ? bdA : bdB; int bj = pAB ? bjA : bjB;

    bool valid = sqrtf(fmaxf(bd, 0.f)) < 1.5f;

    int slab = slabtab[bj];
    if (valid && am != slab) atomicOr(&lbad[bj], 1);   // LDS atomic only
    iv_out[vox] = valid ? bj : -1;

    __syncthreads();
    // compact 512 flags -> 16 bitmap words; plain global stores (no atomics)
    if (tid < 16) {
        unsigned wd = 0;
        #pragma unroll
        for (int i = 0; i < 32; ++i)
            wd |= (lbad[tid * 32 + i] ? 1u : 0u) << i;
        bitmapT[tid * 1024 + B] = wd;
    }
}

// ------- reduce per-block bitmaps -> badw[16] -------
__global__ __launch_bounds__(256) void reduce_bad(const unsigned* __restrict__ bitmapT,
                                                  unsigned* __restrict__ badw) {
    __shared__ unsigned red[256];
    int w = blockIdx.x;      // word 0..15
    int tid = threadIdx.x;
    const unsigned* src = bitmapT + w * 1024;
    unsigned v = src[tid] | src[tid + 256] | src[tid + 512] | src[tid + 768];
    red[tid] = v;
    __syncthreads();
    #pragma unroll
    for (int s = 128; s > 0; s >>= 1) {
        if (tid < s) red[tid] |= red[tid + s];
        __syncthreads();
    }
    if (tid == 0) badw[w] = red[0];
}

// ---------------- finalize pseudo labels (bitmap test) ----------------
__global__ void finalize_kernel(const int* __restrict__ iv,
                                const unsigned* __restrict__ badw,
                                float* __restrict__ pl) {
    int t = blockIdx.x * 256 + threadIdx.x;
    if (t >= NVOX) return;
    int v = iv[t];
    float r = -1.0f;
    if (v >= 0 && !((badw[v >> 5] >> (v & 31)) & 1u)) r = (float)v;
    pl[t] = r;
}

extern "C" void kernel_launch(void* const* d_in, const int* in_sizes, int n_in,
                              void* d_out, int out_size, void* d_ws, size_t ws_size,
                              hipStream_t stream) {
    const float* points   = (const float*)d_in[0];
    const float* features = (const float*)d_in[1];
    const float* ann      = (const float*)d_in[2];
    const float* w1       = (const float*)d_in[3];
    const float* b1       = (const float*)d_in[4];
    const float* w2       = (const float*)d_in[5];
    const float* b2       = (const float*)d_in[6];
    const float* sem_w    = (const float*)d_in[7];
    const float* sem_b    = (const float*)d_in[8];
    const float* off_w    = (const float*)d_in[9];
    const float* off_b    = (const float*)d_in[10];

    float* out        = (float*)d_out;
    float* out_logits = out;
    float* out_off    = out + (size_t)NVOX * NCLS;   // N*20
    float* out_pl     = out + (size_t)NVOX * 23;     // N*23

    // workspace layout (bytes)
    char*  ws  = (char*)d_ws;
    float*          w1t     = (float*)         (ws);             //    41472 B
    unsigned*       badw    = (unsigned*)      (ws + 41472);     //       64 B
    unsigned short* bfr     = (unsigned short*)(ws + 43520);     //   110592 B (hi only)
    int*            iv      = (int*)           (ws + 264704);    //  1048576 B
    float*          seedtab = (float*)         (ws + 1313280);   //     8192 B
    int*            slabtab = (int*)           (ws + 1321472);   //     2048 B
    unsigned*       bitmapT = (unsigned*)      (ws + 1323520);   //    65536 B
    unsigned short* h1hi    = (unsigned short*)(ws + 34867712);  // 33554432 B

    transpose_w1<<<43, 256, 0, stream>>>(w1, w1t, ann, seedtab, slabtab);
    build_bfrags<<<27, 256, 0, stream>>>(w2, bfr);
    conv1_kernel<<<1024, 256, 0, stream>>>(features, w1t, b1, h1hi);
    conv2_fused_kernel<<<1024, 256, 0, stream>>>(h1hi, bfr, b2, seedtab, slabtab,
        points, sem_w, sem_b, off_w, off_b, out_logits, out_off, iv, bitmapT);
    reduce_bad<<<16, 256, 0, stream>>>(bitmapT, badw);
    finalize_kernel<<<1024, 256, 0, stream>>>(iv, badw, out_pl);
}

// Round 20
// 173.956 us; speedup vs baseline: 1.0343x; 1.0343x over previous
//
#include <hip/hip_runtime.h>

#define GRID 64
#define NVOX (GRID*GRID*GRID)
#define NCLS 20
#define NSEED 512

typedef __attribute__((ext_vector_type(8))) short short8_t;
typedef __attribute__((ext_vector_type(4))) float float4_t;

__device__ __forceinline__ unsigned short f32_to_bf16_rne(float f) {
    unsigned int x = __float_as_uint(f);
    unsigned int r = (x + 0x7fffu + ((x >> 16) & 1u)) >> 16;
    return (unsigned short)r;
}
__device__ __forceinline__ float bf16_to_f32(unsigned short u) {
    return __uint_as_float(((unsigned int)u) << 16);
}

// ------- w1 transpose + seed table prep -------
__global__ void transpose_w1(const float* __restrict__ w1, float* __restrict__ w1t,
                             const float* __restrict__ ann, float* __restrict__ seedtab,
                             int* __restrict__ slabtab) {
    int t = blockIdx.x * 256 + threadIdx.x;
    if (t < 27 * 6 * 64) {
        int oc = t & 63;
        int r  = t >> 6;            // nb*6 + ci
        int nb = r / 6, ci = r % 6;
        w1t[t] = w1[oc * 162 + ci * 27 + nb];
        return;
    }
    int i = t - 27 * 6 * 64;
    if (i < NSEED) {
        float a0 = ann[i*4+0], a1 = ann[i*4+1], a2 = ann[i*4+2];
        *reinterpret_cast<float4*>(seedtab + i * 4) =
            make_float4(a0, a1, a2, a0*a0 + a1*a1 + a2*a2);
        slabtab[i] = (int)ann[i*4+3];
    }
}

// ------- build conv2 weight MFMA fragments (bf16 hi only), 108 frags x 1KB -------
// frag f = (nb*2+s)*2+t ; lane l elem j: B[ci=s*32+(l>>4)*8+j][oc=t*16+(l&15)]
__global__ void build_bfrags(const float* __restrict__ w2, unsigned short* __restrict__ bfr) {
    int t = blockIdx.x * 256 + threadIdx.x;      // over 108*64
    if (t >= 108 * 64) return;
    int l  = t & 63;
    int f  = t >> 6;
    int tt = f & 1;
    int s  = (f >> 1) & 1;
    int nb = f >> 2;
    int lr = l & 15, lg = l >> 4;
    int oc = tt * 16 + lr;
    short8_t out;
    #pragma unroll
    for (int j = 0; j < 8; ++j) {
        int ci = s * 32 + lg * 8 + j;
        out[j] = (short)f32_to_bf16_rne(w2[oc * 1728 + ci * 27 + nb]);
    }
    *reinterpret_cast<short8_t*>(bfr + f * 512 + l * 8) = out;
}

// ------- conv1 (6->64): Zd=4, oc-group=8, all-tap LDS weights; 9-tap FULL UNROLL (masked) -------
// grid 2048 = 8 zg x 8 og x 2 zt x 16 yt -> 8 blocks/CU target, 6 waves/SIMD via bounds
// h1 frag layout per (z,y) plane (4096 elems): [xt(4)][s(2)][cc(4)][xl(16)][8ci]
__global__ __launch_bounds__(256, 6) void conv1_kernel(
    const float* __restrict__ feat,   // [6][NVOX]
    const float* __restrict__ w1t,    // [(nb*6+ci)][64]
    const float* __restrict__ b1,
    unsigned short* __restrict__ h1hi)
{
    __shared__ float lw[27 * 6 * 8];  // 5184 B

    int tid = threadIdx.x;
    int B = blockIdx.x;
    int zg = B & 7;
    int k  = B >> 3;                  // 0..255
    int og = k & 7;                   // oc group of 8
    int zt = (k >> 3) & 1;
    int yt = k >> 4;                  // 0..15

    for (int t = tid; t < 27 * 6 * 8; t += 256)
        lw[t] = w1t[(t >> 3) * 64 + og * 8 + (t & 7)];
    __syncthreads();                  // the only barrier

    int x  = tid & 63;
    int y  = yt * 4 + (tid >> 6);     // wave-uniform
    int z0 = zg * 8 + zt * 4;

    float acc[4][8];
    #pragma unroll
    for (int r = 0; r < 4; ++r)
        #pragma unroll
        for (int o = 0; o < 8; ++o) acc[r][o] = 0.f;

    int zoffv[6]; float mzv[6];
    #pragma unroll
    for (int rz = 0; rz < 6; ++rz) {
        int gz = z0 - 1 + rz;
        int cz = gz < 0 ? 0 : (gz > 63 ? 63 : gz);
        zoffv[rz] = cz * 4096;
        mzv[rz] = ((unsigned)gz < 64u) ? 1.f : 0.f;
    }

    // FULL unroll: masked edges (no branches) -> compiler pipelines loads across taps
    #pragma unroll
    for (int dydx = 0; dydx < 9; ++dydx) {
        int dy = dydx / 3 - 1;
        int dx = dydx % 3 - 1;
        int ny = y + dy;
        float my = ((unsigned)ny < 64u) ? 1.f : 0.f;
        int cy = ny < 0 ? 0 : (ny > 63 ? 63 : ny);
        int nx = x + dx;
        float mxv = ((unsigned)nx < 64u) ? 1.f : 0.f;
        int cx = nx < 0 ? 0 : (nx > 63 ? 63 : nx);
        int rowvox = cy * 64 + cx;
        float mxy = mxv * my;

        float cm[6]; int voff[6];
        #pragma unroll
        for (int rz = 0; rz < 6; ++rz) { cm[rz] = mxy * mzv[rz]; voff[rz] = zoffv[rz] + rowvox; }

        #pragma unroll
        for (int cb = 0; cb < 2; ++cb) {
            float v[3][6];
            #pragma unroll
            for (int ci = 0; ci < 3; ++ci) {
                const float* plane = feat + (size_t)(cb * 3 + ci) * NVOX;
                #pragma unroll
                for (int rz = 0; rz < 6; ++rz) v[ci][rz] = plane[voff[rz]];
            }
            #pragma unroll
            for (int ci = 0; ci < 3; ++ci)
                #pragma unroll
                for (int rz = 0; rz < 6; ++rz) v[ci][rz] *= cm[rz];
            #pragma unroll
            for (int ci = 0; ci < 3; ++ci) {
                #pragma unroll
                for (int dzi = 0; dzi < 3; ++dzi) {
                    const float4* wp = reinterpret_cast<const float4*>(
                        &lw[(((dzi * 9 + dydx) * 6) + cb * 3 + ci) * 8]);
                    float4 w0 = wp[0], w1 = wp[1];
                    #pragma unroll
                    for (int r = 0; r < 4; ++r) {
                        float a = v[ci][r + dzi];
                        acc[r][0] = fmaf(a, w0.x, acc[r][0]);
                        acc[r][1] = fmaf(a, w0.y, acc[r][1]);
                        acc[r][2] = fmaf(a, w0.z, acc[r][2]);
                        acc[r][3] = fmaf(a, w0.w, acc[r][3]);
                        acc[r][4] = fmaf(a, w1.x, acc[r][4]);
                        acc[r][5] = fmaf(a, w1.y, acc[r][5]);
                        acc[r][6] = fmaf(a, w1.z, acc[r][6]);
                        acc[r][7] = fmaf(a, w1.w, acc[r][7]);
                    }
                }
            }
        }
    }

    float bias[8];
    #pragma unroll
    for (int o = 0; o < 8; ++o) bias[o] = b1[og * 8 + o];

    // frag-layout store: ci = og*8+o -> s = og>>2, cc = og&3, j = o (one short8 per zl)
    int s1 = og >> 2;
    int c0 = og & 3;
    #pragma unroll
    for (int zl = 0; zl < 4; ++zl) {
        size_t zy = ((size_t)((z0 + zl) * 64 + y)) * 4096;
        size_t base = zy + (size_t)(x >> 4) * 1024 + (size_t)s1 * 512 + (size_t)c0 * 128
                    + (size_t)(x & 15) * 8;
        short8_t hi;
        #pragma unroll
        for (int o = 0; o < 8; ++o)
            hi[o] = (short)f32_to_bf16_rne(fmaxf(acc[zl][o] + bias[o], 0.f));
        *reinterpret_cast<short8_t*>(h1hi + base) = hi;
    }
}

// ------- conv2 (64->32) MFMA (B=bf16) + fused epilogue; 9-row FULL UNROLL (masked) -------
// grid 1024 = 8 zg (XCD, fastest) x 16 yt x 8 zl (slowest)   [R18 configuration]
__global__ __launch_bounds__(256, 4) void conv2_fused_kernel(
    const unsigned short* __restrict__ h1hi, // frag layout
    const unsigned short* __restrict__ bfr,  // [27][2s][2t][64][8] bf16 (hi only)
    const float* __restrict__ b2,
    const float* __restrict__ seedtab,       // [512][4] (x,y,z,|s|^2)
    const int* __restrict__ slabtab,         // [512]
    const float* __restrict__ points,
    const float* __restrict__ sem_w, const float* __restrict__ sem_b,
    const float* __restrict__ off_w, const float* __restrict__ off_b,
    float* __restrict__ out_logits,
    float* __restrict__ out_off,
    int* __restrict__ iv_out,
    unsigned* __restrict__ bitmapT)          // [16 words][1024 blocks]
{
    __shared__ unsigned short smem[4 * 4096]; // per-wave A-row staging; reused as pf store. 32 KB
    __shared__ int lbad[NSEED];               // 2048 B  (total 34 KB -> 4 blocks/CU)

    int tid = threadIdx.x;
    lbad[tid] = 0;
    lbad[tid + 256] = 0;

    int w   = tid >> 6;
    int l   = tid & 63;
    int B   = blockIdx.x;
    int zg  = B & 7;
    int yt  = (B >> 3) & 15;
    int zl  = B >> 7;                 // 0..7 slowest
    int z   = zg * 8 + zl;
    int y   = yt * 4 + w;             // wave-uniform

    int lr = l & 15;
    int lg = l >> 4;

    unsigned short* wsh = &smem[w * 4096];    // this wave's private region

    // per-lane LDS read offsets for shifted fragments: dxs=0 -> dx=-1, dxs=1 -> dx=+1
    int loff[4][2]; bool lok[4][2];
    #pragma unroll
    for (int vt = 0; vt < 4; ++vt) {
        #pragma unroll
        for (int dxs = 0; dxs < 2; ++dxs) {
            int v = vt * 16 + lr + (dxs ? 1 : -1);
            lok[vt][dxs] = (unsigned)v < 64u;
            int vc = v < 0 ? 0 : (v > 63 ? 63 : v);
            loff[vt][dxs] = (vc >> 4) * 1024 + lg * 128 + (vc & 15) * 8;
        }
    }

    // row clamps + validity (block/wave-uniform)
    int czv[3]; bool zokv[3];
    #pragma unroll
    for (int dzi = 0; dzi < 3; ++dzi) {
        int nz = z + dzi - 1;
        zokv[dzi] = (unsigned)nz < 64u;
        czv[dzi] = nz < 0 ? 0 : (nz > 63 ? 63 : nz);
    }
    int cyv[3]; bool yokv[3];
    #pragma unroll
    for (int dyi = 0; dyi < 3; ++dyi) {
        int ny = y + dyi - 1;
        yokv[dyi] = (unsigned)ny < 64u;
        cyv[dyi] = ny < 0 ? 0 : (ny > 63 ? 63 : ny);
    }

    const short8_t zero8 = (short8_t)0;
    float4_t acc[4][2];
    #pragma unroll
    for (int a = 0; a < 4; ++a)
        #pragma unroll
        for (int b = 0; b < 2; ++b) acc[a][b] = (float4_t)0.f;

    // FULL unroll of 9 row-pairs: straight-line code, loads masked not skipped
    #pragma unroll
    for (int dzi = 0; dzi < 3; ++dzi) {
        #pragma unroll
        for (int dyi = 0; dyi < 3; ++dyi) {
            bool rv = zokv[dzi] && yokv[dyi];
            const unsigned short* ph = h1hi + (size_t)(czv[dzi] * 64 + cyv[dyi]) * 4096;

            // ---- stage the dx=0 row: global -> regs (masked) -> wave-private LDS ----
            short8_t ar[4][2];
            #pragma unroll
            for (int vt = 0; vt < 4; ++vt) {
                #pragma unroll
                for (int s = 0; s < 2; ++s) {
                    short8_t t8 = *reinterpret_cast<const short8_t*>(ph + vt * 1024 + s * 512 + l * 8);
                    ar[vt][s] = rv ? t8 : zero8;
                }
            }
            #pragma unroll
            for (int vt = 0; vt < 4; ++vt) {
                #pragma unroll
                for (int s = 0; s < 2; ++s)
                    *reinterpret_cast<short8_t*>(wsh + vt * 1024 + s * 512 + l * 8) = ar[vt][s];
            }
            // same-wave write->read ordered by in-order lgkmcnt (no barrier needed)

            #pragma unroll
            for (int dxm = 0; dxm < 3; ++dxm) {       // compile-time (rule #20)
                int nb = dzi * 9 + dyi * 3 + dxm;
                const unsigned short* bt = bfr + nb * 2048 + l * 8;
                #pragma unroll
                for (int s = 0; s < 2; ++s) {
                    const unsigned short* bs = bt + s * 1024;
                    short8_t bh0 = *reinterpret_cast<const short8_t*>(bs);
                    short8_t bh1 = *reinterpret_cast<const short8_t*>(bs + 512);

                    short8_t a0, a1, a2, a3;
                    if (dxm == 1) {
                        a0 = ar[0][s]; a1 = ar[1][s]; a2 = ar[2][s]; a3 = ar[3][s];
                    } else {
                        int dxs = (dxm == 2) ? 1 : 0;
                        a0 = lok[0][dxs] ? *reinterpret_cast<const short8_t*>(wsh + loff[0][dxs] + s * 512) : zero8;
                        a1 = lok[1][dxs] ? *reinterpret_cast<const short8_t*>(wsh + loff[1][dxs] + s * 512) : zero8;
                        a2 = lok[2][dxs] ? *reinterpret_cast<const short8_t*>(wsh + loff[2][dxs] + s * 512) : zero8;
                        a3 = lok[3][dxs] ? *reinterpret_cast<const short8_t*>(wsh + loff[3][dxs] + s * 512) : zero8;
                    }

                    acc[0][0] = __builtin_amdgcn_mfma_f32_16x16x32_bf16(a0, bh0, acc[0][0], 0, 0, 0);
                    acc[0][1] = __builtin_amdgcn_mfma_f32_16x16x32_bf16(a0, bh1, acc[0][1], 0, 0, 0);
                    acc[1][0] = __builtin_amdgcn_mfma_f32_16x16x32_bf16(a1, bh0, acc[1][0], 0, 0, 0);
                    acc[1][1] = __builtin_amdgcn_mfma_f32_16x16x32_bf16(a1, bh1, acc[1][1], 0, 0, 0);
                    acc[2][0] = __builtin_amdgcn_mfma_f32_16x16x32_bf16(a2, bh0, acc[2][0], 0, 0, 0);
                    acc[2][1] = __builtin_amdgcn_mfma_f32_16x16x32_bf16(a2, bh1, acc[2][1], 0, 0, 0);
                    acc[3][0] = __builtin_amdgcn_mfma_f32_16x16x32_bf16(a3, bh0, acc[3][0], 0, 0, 0);
                    acc[3][1] = __builtin_amdgcn_mfma_f32_16x16x32_bf16(a3, bh1, acc[3][1], 0, 0, 0);
                }
            }
        }
    }

    // ---- bias + relu -> per-wave pf region (bf16, stride 40; region private to this wave) ----
    #pragma unroll
    for (int vt = 0; vt < 4; ++vt) {
        #pragma unroll
        for (int t = 0; t < 2; ++t) {
            float bias = b2[t * 16 + lr];
            #pragma unroll
            for (int r = 0; r < 4; ++r) {
                int vl = vt * 16 + lg * 4 + r;            // voxel within this wave's row
                wsh[vl * 40 + t * 16 + lr] = f32_to_bf16_rne(fmaxf(acc[vt][t][r] + bias, 0.f));
            }
        }
    }
    __syncthreads();   // publishes lbad zero-init (pf stays wave-private)

    // ---- per-thread epilogue: voxel = (z, y of own wave, x = lane) ----
    int ex = tid & 63, ey = yt * 4 + (tid >> 6);
    int vox = (z * 64 + ey) * 64 + ex;

    float f[32];
    #pragma unroll
    for (int q = 0; q < 4; ++q) {
        short8_t v8 = *reinterpret_cast<const short8_t*>(&wsh[(tid & 63) * 40 + q * 8]);
        #pragma unroll
        for (int kk = 0; kk < 8; ++kk) f[q*8+kk] = bf16_to_f32((unsigned short)v8[kk]);
    }

    // semantic head + argmax (wave-uniform weight indices -> s_load; strict > = first occurrence)
    float lbuf[20];
    float best = -1e30f; int am = 0;
    #pragma unroll
    for (int cc = 0; cc < NCLS; ++cc) {
        float a = sem_b[cc];
        #pragma unroll
        for (int q = 0; q < 32; ++q) a = fmaf(f[q], sem_w[cc * 32 + q], a);
        lbuf[cc] = a;
        if (a > best) { best = a; am = cc; }
    }
    #pragma unroll
    for (int q5 = 0; q5 < 5; ++q5)
        *reinterpret_cast<float4*>(out_logits + (size_t)vox * NCLS + q5 * 4) =
            make_float4(lbuf[q5*4], lbuf[q5*4+1], lbuf[q5*4+2], lbuf[q5*4+3]);

    // offset head
    float off[3];
    #pragma unroll
    for (int k3 = 0; k3 < 3; ++k3) {
        float a = off_b[k3];
        #pragma unroll
        for (int q = 0; q < 32; ++q) a = fmaf(f[q], off_w[k3 * 32 + q], a);
        out_off[(size_t)vox * 3 + k3] = a;
        off[k3] = a;
    }

    float px = points[(size_t)vox * 3 + 0] + off[0];
    float py = points[(size_t)vox * 3 + 1] + off[1];
    float pz = points[(size_t)vox * 3 + 2] + off[2];
    float c  = px*px + py*py + pz*pz;
    float mx = -2.f*px, my = -2.f*py, mz = -2.f*pz;

    // seed scan: 4 interleaved chains (ILP on the min dependency), s_load seeds
    float bd0 = 1e30f, bd1 = 1e30f, bd2 = 1e30f, bd3 = 1e30f;
    int   bj0 = 0,     bj1 = 0,     bj2 = 0,     bj3 = 0;
    #pragma unroll 2
    for (int j = 0; j < NSEED; j += 4) {
        float4 s0 = *reinterpret_cast<const float4*>(seedtab + (j + 0) * 4);
        float4 s1 = *reinterpret_cast<const float4*>(seedtab + (j + 1) * 4);
        float4 s2 = *reinterpret_cast<const float4*>(seedtab + (j + 2) * 4);
        float4 s3 = *reinterpret_cast<const float4*>(seedtab + (j + 3) * 4);
        float d0 = fmaf(mx, s0.x, fmaf(my, s0.y, fmaf(mz, s0.z, c + s0.w)));
        float d1 = fmaf(mx, s1.x, fmaf(my, s1.y, fmaf(mz, s1.z, c + s1.w)));
        float d2 = fmaf(mx, s2.x, fmaf(my, s2.y, fmaf(mz, s2.z, c + s2.w)));
        float d3 = fmaf(mx, s3.x, fmaf(my, s3.y, fmaf(mz, s3.z, c + s3.w)));
        if (d0 < bd0) { bd0 = d0; bj0 = j; }          // strict < per chain
        if (d1 < bd1) { bd1 = d1; bj1 = j + 1; }
        if (d2 < bd2) { bd2 = d2; bj2 = j + 2; }
        if (d3 < bd3) { bd3 = d3; bj3 = j + 3; }
    }
    // merge with index tie-break -> global first occurrence
    bool p01 = (bd0 < bd1) || (bd0 == bd1 && bj0 < bj1);
    float bdA = p01 ? bd0 : bd1; int bjA = p01 ? bj0 : bj1;
    bool p23 = (bd2 < bd3) || (bd2 == bd3 && bj2 < bj3);
    float bdB = p23 ? bd2 : bd3; int bjB = p23 ? bj2 : bj3;
    bool pAB = (bdA < bdB) || (bdA == bdB && bjA < bjB);
    float bd = pAB ? bdA : bdB; int bj = pAB ? bjA : bjB;

    bool valid = sqrtf(fmaxf(bd, 0.f)) < 1.5f;

    int slab = slabtab[bj];
    if (valid && am != slab) atomicOr(&lbad[bj], 1);   // LDS atomic only
    iv_out[vox] = valid ? bj : -1;

    __syncthreads();
    // compact 512 flags -> 16 bitmap words; plain global stores (no atomics)
    if (tid < 16) {
        unsigned wd = 0;
        #pragma unroll
        for (int i = 0; i < 32; ++i)
            wd |= (lbad[tid * 32 + i] ? 1u : 0u) << i;
        bitmapT[tid * 1024 + B] = wd;
    }
}

// ------- reduce per-block bitmaps -> badw[16] -------
__global__ __launch_bounds__(256) void reduce_bad(const unsigned* __restrict__ bitmapT,
                                                  unsigned* __restrict__ badw) {
    __shared__ unsigned red[256];
    int w = blockIdx.x;      // word 0..15
    int tid = threadIdx.x;
    const unsigned* src = bitmapT + w * 1024;
    unsigned v = src[tid] | src[tid + 256] | src[tid + 512] | src[tid + 768];
    red[tid] = v;
    __syncthreads();
    #pragma unroll
    for (int s = 128; s > 0; s >>= 1) {
        if (tid < s) red[tid] |= red[tid + s];
        __syncthreads();
    }
    if (tid == 0) badw[w] = red[0];
}

// ---------------- finalize pseudo labels (bitmap test) ----------------
__global__ void finalize_kernel(const int* __restrict__ iv,
                                const unsigned* __restrict__ badw,
                                float* __restrict__ pl) {
    int t = blockIdx.x * 256 + threadIdx.x;
    if (t >= NVOX) return;
    int v = iv[t];
    float r = -1.0f;
    if (v >= 0 && !((badw[v >> 5] >> (v & 31)) & 1u)) r = (float)v;
    pl[t] = r;
}

extern "C" void kernel_launch(void* const* d_in, const int* in_sizes, int n_in,
                              void* d_out, int out_size, void* d_ws, size_t ws_size,
                              hipStream_t stream) {
    const float* points   = (const float*)d_in[0];
    const float* features = (const float*)d_in[1];
    const float* ann      = (const float*)d_in[2];
    const float* w1       = (const float*)d_in[3];
    const float* b1       = (const float*)d_in[4];
    const float* w2       = (const float*)d_in[5];
    const float* b2       = (const float*)d_in[6];
    const float* sem_w    = (const float*)d_in[7];
    const float* sem_b    = (const float*)d_in[8];
    const float* off_w    = (const float*)d_in[9];
    const float* off_b    = (const float*)d_in[10];

    float* out        = (float*)d_out;
    float* out_logits = out;
    float* out_off    = out + (size_t)NVOX * NCLS;   // N*20
    float* out_pl     = out + (size_t)NVOX * 23;     // N*23

    // workspace layout (bytes)
    char*  ws  = (char*)d_ws;
    float*          w1t     = (float*)         (ws);             //    41472 B
    unsigned*       badw    = (unsigned*)      (ws + 41472);     //       64 B
    unsigned short* bfr     = (unsigned short*)(ws + 43520);     //   110592 B (hi only)
    int*            iv      = (int*)           (ws + 264704);    //  1048576 B
    float*          seedtab = (float*)         (ws + 1313280);   //     8192 B
    int*            slabtab = (int*)           (ws + 1321472);   //     2048 B
    unsigned*       bitmapT = (unsigned*)      (ws + 1323520);   //    65536 B
    unsigned short* h1hi    = (unsigned short*)(ws + 34867712);  // 33554432 B

    transpose_w1<<<43, 256, 0, stream>>>(w1, w1t, ann, seedtab, slabtab);
    build_bfrags<<<27, 256, 0, stream>>>(w2, bfr);
    conv1_kernel<<<2048, 256, 0, stream>>>(features, w1t, b1, h1hi);
    conv2_fused_kernel<<<1024, 256, 0, stream>>>(h1hi, bfr, b2, seedtab, slabtab,
        points, sem_w, sem_b, off_w, off_b, out_logits, out_off, iv, bitmapT);
    reduce_bad<<<16, 256, 0, stream>>>(bitmapT, badw);
    finalize_kernel<<<1024, 256, 0, stream>>>(iv, badw, out_pl);
}

// Round 21
// 171.032 us; speedup vs baseline: 1.0519x; 1.0171x over previous
//
#include <hip/hip_runtime.h>

#define GRID 64
#define NVOX (GRID*GRID*GRID)
#define NCLS 20
#define NSEED 512

typedef __attribute__((ext_vector_type(8))) short short8_t;
typedef __attribute__((ext_vector_type(4))) float float4_t;

__device__ __forceinline__ unsigned short f32_to_bf16_rne(float f) {
    unsigned int x = __float_as_uint(f);
    unsigned int r = (x + 0x7fffu + ((x >> 16) & 1u)) >> 16;
    return (unsigned short)r;
}
__device__ __forceinline__ float bf16_to_f32(unsigned short u) {
    return __uint_as_float(((unsigned int)u) << 16);
}

// ------- w1 transpose + seed table prep -------
__global__ void transpose_w1(const float* __restrict__ w1, float* __restrict__ w1t,
                             const float* __restrict__ ann, float* __restrict__ seedtab,
                             int* __restrict__ slabtab) {
    int t = blockIdx.x * 256 + threadIdx.x;
    if (t < 27 * 6 * 64) {
        int oc = t & 63;
        int r  = t >> 6;            // nb*6 + ci
        int nb = r / 6, ci = r % 6;
        w1t[t] = w1[oc * 162 + ci * 27 + nb];
        return;
    }
    int i = t - 27 * 6 * 64;
    if (i < NSEED) {
        float a0 = ann[i*4+0], a1 = ann[i*4+1], a2 = ann[i*4+2];
        *reinterpret_cast<float4*>(seedtab + i * 4) =
            make_float4(a0, a1, a2, a0*a0 + a1*a1 + a2*a2);
        slabtab[i] = (int)ann[i*4+3];
    }
}

// ------- build conv2 weight MFMA fragments (bf16 hi only), 108 frags x 1KB -------
// frag f = (nb*2+s)*2+t ; lane l elem j: B[ci=s*32+(l>>4)*8+j][oc=t*16+(l&15)]
__global__ void build_bfrags(const float* __restrict__ w2, unsigned short* __restrict__ bfr) {
    int t = blockIdx.x * 256 + threadIdx.x;      // over 108*64
    if (t >= 108 * 64) return;
    int l  = t & 63;
    int f  = t >> 6;
    int tt = f & 1;
    int s  = (f >> 1) & 1;
    int nb = f >> 2;
    int lr = l & 15, lg = l >> 4;
    int oc = tt * 16 + lr;
    short8_t out;
    #pragma unroll
    for (int j = 0; j < 8; ++j) {
        int ci = s * 32 + lg * 8 + j;
        out[j] = (short)f32_to_bf16_rne(w2[oc * 1728 + ci * 27 + nb]);
    }
    *reinterpret_cast<short8_t*>(bfr + f * 512 + l * 8) = out;
}

// ------- conv1 (6->64): Zd=8, og=8 (1 weight read feeds 64 FMA -> LDS pipe under cap) -------
// grid 1024 = 8 zg x 8 og x 16 yt ; 9-tap full unroll, masked edges.
// h1 frag layout per (z,y) plane (4096 elems): [xt(4)][s(2)][cc(4)][xl(16)][8ci]
__global__ __launch_bounds__(256, 4) void conv1_kernel(
    const float* __restrict__ feat,   // [6][NVOX]
    const float* __restrict__ w1t,    // [(nb*6+ci)][64]
    const float* __restrict__ b1,
    unsigned short* __restrict__ h1hi)
{
    __shared__ float lw[27 * 6 * 8];  // 5184 B

    int tid = threadIdx.x;
    int B = blockIdx.x;
    int zg = B & 7;
    int k  = B >> 3;                  // 0..127
    int og = k & 7;                   // oc group of 8
    int yt = k >> 3;                  // 0..15

    for (int t = tid; t < 27 * 6 * 8; t += 256)
        lw[t] = w1t[(t >> 3) * 64 + og * 8 + (t & 7)];
    __syncthreads();                  // the only barrier

    int x  = tid & 63;
    int y  = yt * 4 + (tid >> 6);     // wave-uniform
    int z0 = zg * 8;

    float acc[8][8];
    #pragma unroll
    for (int r = 0; r < 8; ++r)
        #pragma unroll
        for (int o = 0; o < 8; ++o) acc[r][o] = 0.f;

    int zoffv[10]; float mzv[10];
    #pragma unroll
    for (int rz = 0; rz < 10; ++rz) {
        int gz = z0 - 1 + rz;
        int cz = gz < 0 ? 0 : (gz > 63 ? 63 : gz);
        zoffv[rz] = cz * 4096;
        mzv[rz] = ((unsigned)gz < 64u) ? 1.f : 0.f;
    }

    // FULL unroll: masked edges (no branches) -> compiler pipelines loads across taps
    #pragma unroll
    for (int dydx = 0; dydx < 9; ++dydx) {
        int dy = dydx / 3 - 1;
        int dx = dydx % 3 - 1;
        int ny = y + dy;
        float my = ((unsigned)ny < 64u) ? 1.f : 0.f;
        int cy = ny < 0 ? 0 : (ny > 63 ? 63 : ny);
        int nx = x + dx;
        float mxv = ((unsigned)nx < 64u) ? 1.f : 0.f;
        int cx = nx < 0 ? 0 : (nx > 63 ? 63 : nx);
        int rowvox = cy * 64 + cx;
        float mxy = mxv * my;

        #pragma unroll
        for (int ci = 0; ci < 6; ++ci) {
            const float* plane = feat + (size_t)ci * NVOX;
            float v[10];
            #pragma unroll
            for (int rz = 0; rz < 10; ++rz) v[rz] = plane[zoffv[rz] + rowvox];
            #pragma unroll
            for (int rz = 0; rz < 10; ++rz) v[rz] *= mxy * mzv[rz];
            #pragma unroll
            for (int dzi = 0; dzi < 3; ++dzi) {
                const float4* wp = reinterpret_cast<const float4*>(
                    &lw[(((dzi * 9 + dydx) * 6) + ci) * 8]);
                float4 w0 = wp[0], w1 = wp[1];
                #pragma unroll
                for (int r = 0; r < 8; ++r) {
                    float a = v[r + dzi];
                    acc[r][0] = fmaf(a, w0.x, acc[r][0]);
                    acc[r][1] = fmaf(a, w0.y, acc[r][1]);
                    acc[r][2] = fmaf(a, w0.z, acc[r][2]);
                    acc[r][3] = fmaf(a, w0.w, acc[r][3]);
                    acc[r][4] = fmaf(a, w1.x, acc[r][4]);
                    acc[r][5] = fmaf(a, w1.y, acc[r][5]);
                    acc[r][6] = fmaf(a, w1.z, acc[r][6]);
                    acc[r][7] = fmaf(a, w1.w, acc[r][7]);
                }
            }
        }
    }

    float bias[8];
    #pragma unroll
    for (int o = 0; o < 8; ++o) bias[o] = b1[og * 8 + o];

    // frag-layout store: ci = og*8+o -> s = og>>2, cc = og&3, j = o (one short8 per zl)
    int s1 = og >> 2;
    int c0 = og & 3;
    #pragma unroll
    for (int zl = 0; zl < 8; ++zl) {
        size_t zy = ((size_t)((z0 + zl) * 64 + y)) * 4096;
        size_t base = zy + (size_t)(x >> 4) * 1024 + (size_t)s1 * 512 + (size_t)c0 * 128
                    + (size_t)(x & 15) * 8;
        short8_t hi;
        #pragma unroll
        for (int o = 0; o < 8; ++o)
            hi[o] = (short)f32_to_bf16_rne(fmaxf(acc[zl][o] + bias[o], 0.f));
        *reinterpret_cast<short8_t*>(h1hi + base) = hi;
    }
}

// ------- conv2 (64->32) MFMA (B=bf16) + fused epilogue; 9-row FULL UNROLL (masked) -------
// grid 1024 = 8 zg (XCD, fastest) x 16 yt x 8 zl (slowest)   [R18 configuration]
__global__ __launch_bounds__(256, 4) void conv2_fused_kernel(
    const unsigned short* __restrict__ h1hi, // frag layout
    const unsigned short* __restrict__ bfr,  // [27][2s][2t][64][8] bf16 (hi only)
    const float* __restrict__ b2,
    const float* __restrict__ seedtab,       // [512][4] (x,y,z,|s|^2)
    const int* __restrict__ slabtab,         // [512]
    const float* __restrict__ points,
    const float* __restrict__ sem_w, const float* __restrict__ sem_b,
    const float* __restrict__ off_w, const float* __restrict__ off_b,
    float* __restrict__ out_logits,
    float* __restrict__ out_off,
    int* __restrict__ iv_out,
    unsigned* __restrict__ bitmapT)          // [16 words][1024 blocks]
{
    __shared__ unsigned short smem[4 * 4096]; // per-wave A-row staging; reused as pf store. 32 KB
    __shared__ int lbad[NSEED];               // 2048 B  (total 34 KB -> 4 blocks/CU)

    int tid = threadIdx.x;
    lbad[tid] = 0;
    lbad[tid + 256] = 0;

    int w   = tid >> 6;
    int l   = tid & 63;
    int B   = blockIdx.x;
    int zg  = B & 7;
    int yt  = (B >> 3) & 15;
    int zl  = B >> 7;                 // 0..7 slowest
    int z   = zg * 8 + zl;
    int y   = yt * 4 + w;             // wave-uniform

    int lr = l & 15;
    int lg = l >> 4;

    unsigned short* wsh = &smem[w * 4096];    // this wave's private region

    // per-lane LDS read offsets for shifted fragments: dxs=0 -> dx=-1, dxs=1 -> dx=+1
    int loff[4][2]; bool lok[4][2];
    #pragma unroll
    for (int vt = 0; vt < 4; ++vt) {
        #pragma unroll
        for (int dxs = 0; dxs < 2; ++dxs) {
            int v = vt * 16 + lr + (dxs ? 1 : -1);
            lok[vt][dxs] = (unsigned)v < 64u;
            int vc = v < 0 ? 0 : (v > 63 ? 63 : v);
            loff[vt][dxs] = (vc >> 4) * 1024 + lg * 128 + (vc & 15) * 8;
        }
    }

    // row clamps + validity (block/wave-uniform)
    int czv[3]; bool zokv[3];
    #pragma unroll
    for (int dzi = 0; dzi < 3; ++dzi) {
        int nz = z + dzi - 1;
        zokv[dzi] = (unsigned)nz < 64u;
        czv[dzi] = nz < 0 ? 0 : (nz > 63 ? 63 : nz);
    }
    int cyv[3]; bool yokv[3];
    #pragma unroll
    for (int dyi = 0; dyi < 3; ++dyi) {
        int ny = y + dyi - 1;
        yokv[dyi] = (unsigned)ny < 64u;
        cyv[dyi] = ny < 0 ? 0 : (ny > 63 ? 63 : ny);
    }

    const short8_t zero8 = (short8_t)0;
    float4_t acc[4][2];
    #pragma unroll
    for (int a = 0; a < 4; ++a)
        #pragma unroll
        for (int b = 0; b < 2; ++b) acc[a][b] = (float4_t)0.f;

    // FULL unroll of 9 row-pairs: straight-line code, loads masked not skipped
    #pragma unroll
    for (int dzi = 0; dzi < 3; ++dzi) {
        #pragma unroll
        for (int dyi = 0; dyi < 3; ++dyi) {
            bool rv = zokv[dzi] && yokv[dyi];
            const unsigned short* ph = h1hi + (size_t)(czv[dzi] * 64 + cyv[dyi]) * 4096;

            // ---- stage the dx=0 row: global -> regs (masked) -> wave-private LDS ----
            short8_t ar[4][2];
            #pragma unroll
            for (int vt = 0; vt < 4; ++vt) {
                #pragma unroll
                for (int s = 0; s < 2; ++s) {
                    short8_t t8 = *reinterpret_cast<const short8_t*>(ph + vt * 1024 + s * 512 + l * 8);
                    ar[vt][s] = rv ? t8 : zero8;
                }
            }
            #pragma unroll
            for (int vt = 0; vt < 4; ++vt) {
                #pragma unroll
                for (int s = 0; s < 2; ++s)
                    *reinterpret_cast<short8_t*>(wsh + vt * 1024 + s * 512 + l * 8) = ar[vt][s];
            }
            // same-wave write->read ordered by in-order lgkmcnt (no barrier needed)

            #pragma unroll
            for (int dxm = 0; dxm < 3; ++dxm) {       // compile-time (rule #20)
                int nb = dzi * 9 + dyi * 3 + dxm;
                const unsigned short* bt = bfr + nb * 2048 + l * 8;
                #pragma unroll
                for (int s = 0; s < 2; ++s) {
                    const unsigned short* bs = bt + s * 1024;
                    short8_t bh0 = *reinterpret_cast<const short8_t*>(bs);
                    short8_t bh1 = *reinterpret_cast<const short8_t*>(bs + 512);

                    short8_t a0, a1, a2, a3;
                    if (dxm == 1) {
                        a0 = ar[0][s]; a1 = ar[1][s]; a2 = ar[2][s]; a3 = ar[3][s];
                    } else {
                        int dxs = (dxm == 2) ? 1 : 0;
                        a0 = lok[0][dxs] ? *reinterpret_cast<const short8_t*>(wsh + loff[0][dxs] + s * 512) : zero8;
                        a1 = lok[1][dxs] ? *reinterpret_cast<const short8_t*>(wsh + loff[1][dxs] + s * 512) : zero8;
                        a2 = lok[2][dxs] ? *reinterpret_cast<const short8_t*>(wsh + loff[2][dxs] + s * 512) : zero8;
                        a3 = lok[3][dxs] ? *reinterpret_cast<const short8_t*>(wsh + loff[3][dxs] + s * 512) : zero8;
                    }

                    acc[0][0] = __builtin_amdgcn_mfma_f32_16x16x32_bf16(a0, bh0, acc[0][0], 0, 0, 0);
                    acc[0][1] = __builtin_amdgcn_mfma_f32_16x16x32_bf16(a0, bh1, acc[0][1], 0, 0, 0);
                    acc[1][0] = __builtin_amdgcn_mfma_f32_16x16x32_bf16(a1, bh0, acc[1][0], 0, 0, 0);
                    acc[1][1] = __builtin_amdgcn_mfma_f32_16x16x32_bf16(a1, bh1, acc[1][1], 0, 0, 0);
                    acc[2][0] = __builtin_amdgcn_mfma_f32_16x16x32_bf16(a2, bh0, acc[2][0], 0, 0, 0);
                    acc[2][1] = __builtin_amdgcn_mfma_f32_16x16x32_bf16(a2, bh1, acc[2][1], 0, 0, 0);
                    acc[3][0] = __builtin_amdgcn_mfma_f32_16x16x32_bf16(a3, bh0, acc[3][0], 0, 0, 0);
                    acc[3][1] = __builtin_amdgcn_mfma_f32_16x16x32_bf16(a3, bh1, acc[3][1], 0, 0, 0);
                }
            }
        }
    }

    // ---- bias + relu -> per-wave pf region (bf16, stride 40; region private to this wave) ----
    #pragma unroll
    for (int vt = 0; vt < 4; ++vt) {
        #pragma unroll
        for (int t = 0; t < 2; ++t) {
            float bias = b2[t * 16 + lr];
            #pragma unroll
            for (int r = 0; r < 4; ++r) {
                int vl = vt * 16 + lg * 4 + r;            // voxel within this wave's row
                wsh[vl * 40 + t * 16 + lr] = f32_to_bf16_rne(fmaxf(acc[vt][t][r] + bias, 0.f));
            }
        }
    }
    __syncthreads();   // publishes lbad zero-init (pf stays wave-private)

    // ---- per-thread epilogue: voxel = (z, y of own wave, x = lane) ----
    int ex = tid & 63, ey = yt * 4 + (tid >> 6);
    int vox = (z * 64 + ey) * 64 + ex;

    float f[32];
    #pragma unroll
    for (int q = 0; q < 4; ++q) {
        short8_t v8 = *reinterpret_cast<const short8_t*>(&wsh[(tid & 63) * 40 + q * 8]);
        #pragma unroll
        for (int kk = 0; kk < 8; ++kk) f[q*8+kk] = bf16_to_f32((unsigned short)v8[kk]);
    }

    // semantic head + argmax (wave-uniform weight indices -> s_load; strict > = first occurrence)
    float lbuf[20];
    float best = -1e30f; int am = 0;
    #pragma unroll
    for (int cc = 0; cc < NCLS; ++cc) {
        float a = sem_b[cc];
        #pragma unroll
        for (int q = 0; q < 32; ++q) a = fmaf(f[q], sem_w[cc * 32 + q], a);
        lbuf[cc] = a;
        if (a > best) { best = a; am = cc; }
    }
    #pragma unroll
    for (int q5 = 0; q5 < 5; ++q5)
        *reinterpret_cast<float4*>(out_logits + (size_t)vox * NCLS + q5 * 4) =
            make_float4(lbuf[q5*4], lbuf[q5*4+1], lbuf[q5*4+2], lbuf[q5*4+3]);

    // offset head
    float off[3];
    #pragma unroll
    for (int k3 = 0; k3 < 3; ++k3) {
        float a = off_b[k3];
        #pragma unroll
        for (int q = 0; q < 32; ++q) a = fmaf(f[q], off_w[k3 * 32 + q], a);
        out_off[(size_t)vox * 3 + k3] = a;
        off[k3] = a;
    }

    float px = points[(size_t)vox * 3 + 0] + off[0];
    float py = points[(size_t)vox * 3 + 1] + off[1];
    float pz = points[(size_t)vox * 3 + 2] + off[2];
    float c  = px*px + py*py + pz*pz;
    float mx = -2.f*px, my = -2.f*py, mz = -2.f*pz;

    // seed scan: 4 interleaved chains (ILP on the min dependency), s_load seeds
    float bd0 = 1e30f, bd1 = 1e30f, bd2 = 1e30f, bd3 = 1e30f;
    int   bj0 = 0,     bj1 = 0,     bj2 = 0,     bj3 = 0;
    #pragma unroll 2
    for (int j = 0; j < NSEED; j += 4) {
        float4 s0 = *reinterpret_cast<const float4*>(seedtab + (j + 0) * 4);
        float4 s1 = *reinterpret_cast<const float4*>(seedtab + (j + 1) * 4);
        float4 s2 = *reinterpret_cast<const float4*>(seedtab + (j + 2) * 4);
        float4 s3 = *reinterpret_cast<const float4*>(seedtab + (j + 3) * 4);
        float d0 = fmaf(mx, s0.x, fmaf(my, s0.y, fmaf(mz, s0.z, c + s0.w)));
        float d1 = fmaf(mx, s1.x, fmaf(my, s1.y, fmaf(mz, s1.z, c + s1.w)));
        float d2 = fmaf(mx, s2.x, fmaf(my, s2.y, fmaf(mz, s2.z, c + s2.w)));
        float d3 = fmaf(mx, s3.x, fmaf(my, s3.y, fmaf(mz, s3.z, c + s3.w)));
        if (d0 < bd0) { bd0 = d0; bj0 = j; }          // strict < per chain
        if (d1 < bd1) { bd1 = d1; bj1 = j + 1; }
        if (d2 < bd2) { bd2 = d2; bj2 = j + 2; }
        if (d3 < bd3) { bd3 = d3; bj3 = j + 3; }
    }
    // merge with index tie-break -> global first occurrence
    bool p01 = (bd0 < bd1) || (bd0 == bd1 && bj0 < bj1);
    float bdA = p01 ? bd0 : bd1; int bjA = p01 ? bj0 : bj1;
    bool p23 = (bd2 < bd3) || (bd2 == bd3 && bj2 < bj3);
    float bdB = p23 ? bd2 : bd3; int bjB = p23 ? bj2 : bj3;
    bool pAB = (bdA < bdB) || (bdA == bdB && bjA < bjB);
    float bd = pAB ? bdA : bdB; int bj = pAB ? bjA : bjB;

    bool valid = sqrtf(fmaxf(bd, 0.f)) < 1.5f;

    int slab = slabtab[bj];
    if (valid && am != slab) atomicOr(&lbad[bj], 1);   // LDS atomic only
    iv_out[vox] = valid ? bj : -1;

    __syncthreads();
    // compact 512 flags -> 16 bitmap words; plain global stores (no atomics)
    if (tid < 16) {
        unsigned wd = 0;
        #pragma unroll
        for (int i = 0; i < 32; ++i)
            wd |= (lbad[tid * 32 + i] ? 1u : 0u) << i;
        bitmapT[tid * 1024 + B] = wd;
    }
}

// ------- reduce per-block bitmaps -> badw[16] -------
__global__ __launch_bounds__(256) void reduce_bad(const unsigned* __restrict__ bitmapT,
                                                  unsigned* __restrict__ badw) {
    __shared__ unsigned red[256];
    int w = blockIdx.x;      // word 0..15
    int tid = threadIdx.x;
    const unsigned* src = bitmapT + w * 1024;
    unsigned v = src[tid] | src[tid + 256] | src[tid + 512] | src[tid + 768];
    red[tid] = v;
    __syncthreads();
    #pragma unroll
    for (int s = 128; s > 0; s >>= 1) {
        if (tid < s) red[tid] |= red[tid + s];
        __syncthreads();
    }
    if (tid == 0) badw[w] = red[0];
}

// ---------------- finalize pseudo labels (bitmap test) ----------------
__global__ void finalize_kernel(const int* __restrict__ iv,
                                const unsigned* __restrict__ badw,
                                float* __restrict__ pl) {
    int t = blockIdx.x * 256 + threadIdx.x;
    if (t >= NVOX) return;
    int v = iv[t];
    float r = -1.0f;
    if (v >= 0 && !((badw[v >> 5] >> (v & 31)) & 1u)) r = (float)v;
    pl[t] = r;
}

extern "C" void kernel_launch(void* const* d_in, const int* in_sizes, int n_in,
                              void* d_out, int out_size, void* d_ws, size_t ws_size,
                              hipStream_t stream) {
    const float* points   = (const float*)d_in[0];
    const float* features = (const float*)d_in[1];
    const float* ann      = (const float*)d_in[2];
    const float* w1       = (const float*)d_in[3];
    const float* b1       = (const float*)d_in[4];
    const float* w2       = (const float*)d_in[5];
    const float* b2       = (const float*)d_in[6];
    const float* sem_w    = (const float*)d_in[7];
    const float* sem_b    = (const float*)d_in[8];
    const float* off_w    = (const float*)d_in[9];
    const float* off_b    = (const float*)d_in[10];

    float* out        = (float*)d_out;
    float* out_logits = out;
    float* out_off    = out + (size_t)NVOX * NCLS;   // N*20
    float* out_pl     = out + (size_t)NVOX * 23;     // N*23

    // workspace layout (bytes)
    char*  ws  = (char*)d_ws;
    float*          w1t     = (float*)         (ws);             //    41472 B
    unsigned*       badw    = (unsigned*)      (ws + 41472);     //       64 B
    unsigned short* bfr     = (unsigned short*)(ws + 43520);     //   110592 B (hi only)
    int*            iv      = (int*)           (ws + 264704);    //  1048576 B
    float*          seedtab = (float*)         (ws + 1313280);   //     8192 B
    int*            slabtab = (int*)           (ws + 1321472);   //     2048 B
    unsigned*       bitmapT = (unsigned*)      (ws + 1323520);   //    65536 B
    unsigned short* h1hi    = (unsigned short*)(ws + 34867712);  // 33554432 B

    transpose_w1<<<43, 256, 0, stream>>>(w1, w1t, ann, seedtab, slabtab);
    build_bfrags<<<27, 256, 0, stream>>>(w2, bfr);
    conv1_kernel<<<1024, 256, 0, stream>>>(features, w1t, b1, h1hi);
    conv2_fused_kernel<<<1024, 256, 0, stream>>>(h1hi, bfr, b2, seedtab, slabtab,
        points, sem_w, sem_b, off_w, off_b, out_logits, out_off, iv, bitmapT);
    reduce_bad<<<16, 256, 0, stream>>>(bitmapT, badw);
    finalize_kernel<<<1024, 256, 0, stream>>>(iv, badw, out_pl);
}

// Round 22
// 170.222 us; speedup vs baseline: 1.0570x; 1.0048x over previous
//
#include <hip/hip_runtime.h>

#define GRID 64
#define NVOX (GRID*GRID*GRID)
#define NCLS 20
#define NSEED 512

typedef __attribute__((ext_vector_type(8))) short short8_t;
typedef __attribute__((ext_vector_type(4))) float float4_t;

__device__ __forceinline__ unsigned short f32_to_bf16_rne(float f) {
    unsigned int x = __float_as_uint(f);
    unsigned int r = (x + 0x7fffu + ((x >> 16) & 1u)) >> 16;
    return (unsigned short)r;
}
__device__ __forceinline__ float bf16_to_f32(unsigned short u) {
    return __uint_as_float(((unsigned int)u) << 16);
}

// ------- w1 transpose + seed table prep -------
__global__ void transpose_w1(const float* __restrict__ w1, float* __restrict__ w1t,
                             const float* __restrict__ ann, float* __restrict__ seedtab,
                             int* __restrict__ slabtab) {
    int t = blockIdx.x * 256 + threadIdx.x;
    if (t < 27 * 6 * 64) {
        int oc = t & 63;
        int r  = t >> 6;            // nb*6 + ci
        int nb = r / 6, ci = r % 6;
        w1t[t] = w1[oc * 162 + ci * 27 + nb];
        return;
    }
    int i = t - 27 * 6 * 64;
    if (i < NSEED) {
        float a0 = ann[i*4+0], a1 = ann[i*4+1], a2 = ann[i*4+2];
        *reinterpret_cast<float4*>(seedtab + i * 4) =
            make_float4(a0, a1, a2, a0*a0 + a1*a1 + a2*a2);
        slabtab[i] = (int)ann[i*4+3];
    }
}

// ------- build conv2 weight MFMA fragments (bf16 hi only), 108 frags x 1KB -------
// frag f = (nb*2+s)*2+t ; lane l elem j: B[ci=s*32+(l>>4)*8+j][oc=t*16+(l&15)]
__global__ void build_bfrags(const float* __restrict__ w2, unsigned short* __restrict__ bfr) {
    int t = blockIdx.x * 256 + threadIdx.x;      // over 108*64
    if (t >= 108 * 64) return;
    int l  = t & 63;
    int f  = t >> 6;
    int tt = f & 1;
    int s  = (f >> 1) & 1;
    int nb = f >> 2;
    int lr = l & 15, lg = l >> 4;
    int oc = tt * 16 + lr;
    short8_t out;
    #pragma unroll
    for (int j = 0; j < 8; ++j) {
        int ci = s * 32 + lg * 8 + j;
        out[j] = (short)f32_to_bf16_rne(w2[oc * 1728 + ci * 27 + nb]);
    }
    *reinterpret_cast<short8_t*>(bfr + f * 512 + l * 8) = out;
}

// ------- conv1 (6->64): Zd=4, oc=16, all-tap LDS weights; 9-tap FULL UNROLL (masked) -------
// h1 frag layout per (z,y) plane (4096 elems): [xt(4)][s(2)][cc(4)][xl(16)][8ci]
__global__ __launch_bounds__(256, 4) void conv1_kernel(
    const float* __restrict__ feat,   // [6][NVOX]
    const float* __restrict__ w1t,    // [(nb*6+ci)][64]
    const float* __restrict__ b1,
    unsigned short* __restrict__ h1hi)
{
    __shared__ float lw[27 * 6 * 16]; // 10368 B

    int tid = threadIdx.x;
    int B = blockIdx.x;
    int zg = B & 7;
    int k  = B >> 3;
    int og = k & 3;                   // oc group of 16
    int zt = (k >> 2) & 1;
    int yt = (k >> 3) & 15;

    for (int t = tid; t < 27 * 6 * 16; t += 256)
        lw[t] = w1t[(t >> 4) * 64 + og * 16 + (t & 15)];
    __syncthreads();                  // the only barrier

    int x  = tid & 63;
    int y  = yt * 4 + (tid >> 6);     // wave-uniform
    int z0 = zg * 8 + zt * 4;

    float acc[4][16];
    #pragma unroll
    for (int r = 0; r < 4; ++r)
        #pragma unroll
        for (int o = 0; o < 16; ++o) acc[r][o] = 0.f;

    int zoffv[6]; float mzv[6];
    #pragma unroll
    for (int rz = 0; rz < 6; ++rz) {
        int gz = z0 - 1 + rz;
        int cz = gz < 0 ? 0 : (gz > 63 ? 63 : gz);
        zoffv[rz] = cz * 4096;
        mzv[rz] = ((unsigned)gz < 64u) ? 1.f : 0.f;
    }

    // FULL unroll: masked edges (no branches) -> compiler pipelines loads across taps
    #pragma unroll
    for (int dydx = 0; dydx < 9; ++dydx) {
        int dy = dydx / 3 - 1;
        int dx = dydx % 3 - 1;
        int ny = y + dy;
        float my = ((unsigned)ny < 64u) ? 1.f : 0.f;
        int cy = ny < 0 ? 0 : (ny > 63 ? 63 : ny);
        int nx = x + dx;
        float mxv = ((unsigned)nx < 64u) ? 1.f : 0.f;
        int cx = nx < 0 ? 0 : (nx > 63 ? 63 : nx);
        int rowvox = cy * 64 + cx;
        float mxy = mxv * my;

        float cm[6]; int voff[6];
        #pragma unroll
        for (int rz = 0; rz < 6; ++rz) { cm[rz] = mxy * mzv[rz]; voff[rz] = zoffv[rz] + rowvox; }

        #pragma unroll
        for (int cb = 0; cb < 2; ++cb) {
            float v[3][6];
            #pragma unroll
            for (int ci = 0; ci < 3; ++ci) {
                const float* plane = feat + (size_t)(cb * 3 + ci) * NVOX;
                #pragma unroll
                for (int rz = 0; rz < 6; ++rz) v[ci][rz] = plane[voff[rz]];
            }
            #pragma unroll
            for (int ci = 0; ci < 3; ++ci)
                #pragma unroll
                for (int rz = 0; rz < 6; ++rz) v[ci][rz] *= cm[rz];
            #pragma unroll
            for (int ci = 0; ci < 3; ++ci) {
                #pragma unroll
                for (int dzi = 0; dzi < 3; ++dzi) {
                    const float4* wp = reinterpret_cast<const float4*>(
                        &lw[(((dzi * 9 + dydx) * 6) + cb * 3 + ci) * 16]);
                    float4 w0 = wp[0], w1 = wp[1], w2 = wp[2], w3 = wp[3];
                    #pragma unroll
                    for (int r = 0; r < 4; ++r) {
                        float a = v[ci][r + dzi];
                        acc[r][0]  = fmaf(a, w0.x, acc[r][0]);
                        acc[r][1]  = fmaf(a, w0.y, acc[r][1]);
                        acc[r][2]  = fmaf(a, w0.z, acc[r][2]);
                        acc[r][3]  = fmaf(a, w0.w, acc[r][3]);
                        acc[r][4]  = fmaf(a, w1.x, acc[r][4]);
                        acc[r][5]  = fmaf(a, w1.y, acc[r][5]);
                        acc[r][6]  = fmaf(a, w1.z, acc[r][6]);
                        acc[r][7]  = fmaf(a, w1.w, acc[r][7]);
                        acc[r][8]  = fmaf(a, w2.x, acc[r][8]);
                        acc[r][9]  = fmaf(a, w2.y, acc[r][9]);
                        acc[r][10] = fmaf(a, w2.z, acc[r][10]);
                        acc[r][11] = fmaf(a, w2.w, acc[r][11]);
                        acc[r][12] = fmaf(a, w3.x, acc[r][12]);
                        acc[r][13] = fmaf(a, w3.y, acc[r][13]);
                        acc[r][14] = fmaf(a, w3.z, acc[r][14]);
                        acc[r][15] = fmaf(a, w3.w, acc[r][15]);
                    }
                }
            }
        }
    }

    float bias[16];
    #pragma unroll
    for (int o = 0; o < 16; ++o) bias[o] = b1[og * 16 + o];

    // frag-layout store (hi only): s = og>>1; cc = (og*2 + (o>>3)) & 3
    int s1 = og >> 1;
    int c0 = (og * 2) & 3;
    int c1 = (og * 2 + 1) & 3;
    #pragma unroll
    for (int zl = 0; zl < 4; ++zl) {
        size_t zy = ((size_t)((z0 + zl) * 64 + y)) * 4096;
        size_t base  = zy + (size_t)(x >> 4) * 1024 + (size_t)s1 * 512 + (size_t)(x & 15) * 8;
        short8_t hi0, hi1;
        #pragma unroll
        for (int o = 0; o < 8; ++o)
            hi0[o] = (short)f32_to_bf16_rne(fmaxf(acc[zl][o] + bias[o], 0.f));
        #pragma unroll
        for (int o = 8; o < 16; ++o)
            hi1[o - 8] = (short)f32_to_bf16_rne(fmaxf(acc[zl][o] + bias[o], 0.f));
        *reinterpret_cast<short8_t*>(h1hi + base + c0 * 128) = hi0;
        *reinterpret_cast<short8_t*>(h1hi + base + c1 * 128) = hi1;
    }
}

// ------- conv2 (64->32) MFMA (B=bf16) + fused epilogue; 9-row FULL UNROLL (masked) -------
// grid 1024 = 8 zg (XCD, fastest) x 16 yt x 8 zl (slowest)
__global__ __launch_bounds__(256, 4) void conv2_fused_kernel(
    const unsigned short* __restrict__ h1hi, // frag layout
    const unsigned short* __restrict__ bfr,  // [27][2s][2t][64][8] bf16 (hi only)
    const float* __restrict__ b2,
    const float* __restrict__ seedtab,       // [512][4] (x,y,z,|s|^2)
    const int* __restrict__ slabtab,         // [512]
    const float* __restrict__ points,
    const float* __restrict__ sem_w, const float* __restrict__ sem_b,
    const float* __restrict__ off_w, const float* __restrict__ off_b,
    float* __restrict__ out_logits,
    float* __restrict__ out_off,
    int* __restrict__ iv_out,
    unsigned* __restrict__ bitmapT)          // [16 words][1024 blocks]
{
    __shared__ unsigned short smem[4 * 4096]; // per-wave A-row staging; reused as pf store. 32 KB
    __shared__ int lbad[NSEED];               // 2048 B  (total 34 KB -> 4 blocks/CU)

    int tid = threadIdx.x;
    lbad[tid] = 0;
    lbad[tid + 256] = 0;

    int w   = tid >> 6;
    int l   = tid & 63;
    int B   = blockIdx.x;
    int zg  = B & 7;
    int yt  = (B >> 3) & 15;
    int zl  = B >> 7;                 // 0..7 slowest
    int z   = zg * 8 + zl;
    int y   = yt * 4 + w;             // wave-uniform

    int lr = l & 15;
    int lg = l >> 4;

    unsigned short* wsh = &smem[w * 4096];    // this wave's private region

    // per-lane LDS read offsets for shifted fragments: dxs=0 -> dx=-1, dxs=1 -> dx=+1
    int loff[4][2]; bool lok[4][2];
    #pragma unroll
    for (int vt = 0; vt < 4; ++vt) {
        #pragma unroll
        for (int dxs = 0; dxs < 2; ++dxs) {
            int v = vt * 16 + lr + (dxs ? 1 : -1);
            lok[vt][dxs] = (unsigned)v < 64u;
            int vc = v < 0 ? 0 : (v > 63 ? 63 : v);
            loff[vt][dxs] = (vc >> 4) * 1024 + lg * 128 + (vc & 15) * 8;
        }
    }

    // row clamps + validity (block/wave-uniform)
    int czv[3]; bool zokv[3];
    #pragma unroll
    for (int dzi = 0; dzi < 3; ++dzi) {
        int nz = z + dzi - 1;
        zokv[dzi] = (unsigned)nz < 64u;
        czv[dzi] = nz < 0 ? 0 : (nz > 63 ? 63 : nz);
    }
    int cyv[3]; bool yokv[3];
    #pragma unroll
    for (int dyi = 0; dyi < 3; ++dyi) {
        int ny = y + dyi - 1;
        yokv[dyi] = (unsigned)ny < 64u;
        cyv[dyi] = ny < 0 ? 0 : (ny > 63 ? 63 : ny);
    }

    const short8_t zero8 = (short8_t)0;
    float4_t acc[4][2];
    #pragma unroll
    for (int a = 0; a < 4; ++a)
        #pragma unroll
        for (int b = 0; b < 2; ++b) acc[a][b] = (float4_t)0.f;

    // FULL unroll of 9 row-pairs: straight-line code, loads masked not skipped
    #pragma unroll
    for (int dzi = 0; dzi < 3; ++dzi) {
        #pragma unroll
        for (int dyi = 0; dyi < 3; ++dyi) {
            bool rv = zokv[dzi] && yokv[dyi];
            const unsigned short* ph = h1hi + (size_t)(czv[dzi] * 64 + cyv[dyi]) * 4096;

            // ---- stage the dx=0 row: global -> regs (masked) -> wave-private LDS ----
            short8_t ar[4][2];
            #pragma unroll
            for (int vt = 0; vt < 4; ++vt) {
                #pragma unroll
                for (int s = 0; s < 2; ++s) {
                    short8_t t8 = *reinterpret_cast<const short8_t*>(ph + vt * 1024 + s * 512 + l * 8);
                    ar[vt][s] = rv ? t8 : zero8;
                }
            }
            #pragma unroll
            for (int vt = 0; vt < 4; ++vt) {
                #pragma unroll
                for (int s = 0; s < 2; ++s)
                    *reinterpret_cast<short8_t*>(wsh + vt * 1024 + s * 512 + l * 8) = ar[vt][s];
            }
            // same-wave write->read ordered by in-order lgkmcnt (no barrier needed)

            #pragma unroll
            for (int dxm = 0; dxm < 3; ++dxm) {       // compile-time (rule #20)
                int nb = dzi * 9 + dyi * 3 + dxm;
                const unsigned short* bt = bfr + nb * 2048 + l * 8;
                #pragma unroll
                for (int s = 0; s < 2; ++s) {
                    const unsigned short* bs = bt + s * 1024;
                    short8_t bh0 = *reinterpret_cast<const short8_t*>(bs);
                    short8_t bh1 = *reinterpret_cast<const short8_t*>(bs + 512);

                    short8_t a0, a1, a2, a3;
                    if (dxm == 1) {
                        a0 = ar[0][s]; a1 = ar[1][s]; a2 = ar[2][s]; a3 = ar[3][s];
                    } else {
                        int dxs = (dxm == 2) ? 1 : 0;
                        a0 = lok[0][dxs] ? *reinterpret_cast<const short8_t*>(wsh + loff[0][dxs] + s * 512) : zero8;
                        a1 = lok[1][dxs] ? *reinterpret_cast<const short8_t*>(wsh + loff[1][dxs] + s * 512) : zero8;
                        a2 = lok[2][dxs] ? *reinterpret_cast<const short8_t*>(wsh + loff[2][dxs] + s * 512) : zero8;
                        a3 = lok[3][dxs] ? *reinterpret_cast<const short8_t*>(wsh + loff[3][dxs] + s * 512) : zero8;
                    }

                    acc[0][0] = __builtin_amdgcn_mfma_f32_16x16x32_bf16(a0, bh0, acc[0][0], 0, 0, 0);
                    acc[0][1] = __builtin_amdgcn_mfma_f32_16x16x32_bf16(a0, bh1, acc[0][1], 0, 0, 0);
                    acc[1][0] = __builtin_amdgcn_mfma_f32_16x16x32_bf16(a1, bh0, acc[1][0], 0, 0, 0);
                    acc[1][1] = __builtin_amdgcn_mfma_f32_16x16x32_bf16(a1, bh1, acc[1][1], 0, 0, 0);
                    acc[2][0] = __builtin_amdgcn_mfma_f32_16x16x32_bf16(a2, bh0, acc[2][0], 0, 0, 0);
                    acc[2][1] = __builtin_amdgcn_mfma_f32_16x16x32_bf16(a2, bh1, acc[2][1], 0, 0, 0);
                    acc[3][0] = __builtin_amdgcn_mfma_f32_16x16x32_bf16(a3, bh0, acc[3][0], 0, 0, 0);
                    acc[3][1] = __builtin_amdgcn_mfma_f32_16x16x32_bf16(a3, bh1, acc[3][1], 0, 0, 0);
                }
            }
        }
    }

    // ---- bias + relu -> per-wave pf region (bf16, stride 40; region private to this wave) ----
    #pragma unroll
    for (int vt = 0; vt < 4; ++vt) {
        #pragma unroll
        for (int t = 0; t < 2; ++t) {
            float bias = b2[t * 16 + lr];
            #pragma unroll
            for (int r = 0; r < 4; ++r) {
                int vl = vt * 16 + lg * 4 + r;            // voxel within this wave's row
                wsh[vl * 40 + t * 16 + lr] = f32_to_bf16_rne(fmaxf(acc[vt][t][r] + bias, 0.f));
            }
        }
    }
    __syncthreads();   // publishes lbad zero-init (pf stays wave-private)

    // ---- per-thread epilogue: voxel = (z, y of own wave, x = lane) ----
    int ex = tid & 63, ey = yt * 4 + (tid >> 6);
    int vox = (z * 64 + ey) * 64 + ex;

    float f[32];
    #pragma unroll
    for (int q = 0; q < 4; ++q) {
        short8_t v8 = *reinterpret_cast<const short8_t*>(&wsh[(tid & 63) * 40 + q * 8]);
        #pragma unroll
        for (int kk = 0; kk < 8; ++kk) f[q*8+kk] = bf16_to_f32((unsigned short)v8[kk]);
    }

    // semantic head + argmax (wave-uniform weight indices -> s_load; strict > = first occurrence)
    float lbuf[20];
    float best = -1e30f; int am = 0;
    #pragma unroll
    for (int cc = 0; cc < NCLS; ++cc) {
        float a = sem_b[cc];
        #pragma unroll
        for (int q = 0; q < 32; ++q) a = fmaf(f[q], sem_w[cc * 32 + q], a);
        lbuf[cc] = a;
        if (a > best) { best = a; am = cc; }
    }
    #pragma unroll
    for (int q5 = 0; q5 < 5; ++q5)
        *reinterpret_cast<float4*>(out_logits + (size_t)vox * NCLS + q5 * 4) =
            make_float4(lbuf[q5*4], lbuf[q5*4+1], lbuf[q5*4+2], lbuf[q5*4+3]);

    // offset head
    float off[3];
    #pragma unroll
    for (int k3 = 0; k3 < 3; ++k3) {
        float a = off_b[k3];
        #pragma unroll
        for (int q = 0; q < 32; ++q) a = fmaf(f[q], off_w[k3 * 32 + q], a);
        out_off[(size_t)vox * 3 + k3] = a;
        off[k3] = a;
    }

    float px = points[(size_t)vox * 3 + 0] + off[0];
    float py = points[(size_t)vox * 3 + 1] + off[1];
    float pz = points[(size_t)vox * 3 + 2] + off[2];
    float c  = px*px + py*py + pz*pz;
    float mx = -2.f*px, my = -2.f*py, mz = -2.f*pz;

    // seed scan: 4 interleaved chains (ILP on the min dependency), s_load seeds
    float bd0 = 1e30f, bd1 = 1e30f, bd2 = 1e30f, bd3 = 1e30f;
    int   bj0 = 0,     bj1 = 0,     bj2 = 0,     bj3 = 0;
    #pragma unroll 2
    for (int j = 0; j < NSEED; j += 4) {
        float4 s0 = *reinterpret_cast<const float4*>(seedtab + (j + 0) * 4);
        float4 s1 = *reinterpret_cast<const float4*>(seedtab + (j + 1) * 4);
        float4 s2 = *reinterpret_cast<const float4*>(seedtab + (j + 2) * 4);
        float4 s3 = *reinterpret_cast<const float4*>(seedtab + (j + 3) * 4);
        float d0 = fmaf(mx, s0.x, fmaf(my, s0.y, fmaf(mz, s0.z, c + s0.w)));
        float d1 = fmaf(mx, s1.x, fmaf(my, s1.y, fmaf(mz, s1.z, c + s1.w)));
        float d2 = fmaf(mx, s2.x, fmaf(my, s2.y, fmaf(mz, s2.z, c + s2.w)));
        float d3 = fmaf(mx, s3.x, fmaf(my, s3.y, fmaf(mz, s3.z, c + s3.w)));
        if (d0 < bd0) { bd0 = d0; bj0 = j; }          // strict < per chain
        if (d1 < bd1) { bd1 = d1; bj1 = j + 1; }
        if (d2 < bd2) { bd2 = d2; bj2 = j + 2; }
        if (d3 < bd3) { bd3 = d3; bj3 = j + 3; }
    }
    // merge with index tie-break -> global first occurrence
    bool p01 = (bd0 < bd1) || (bd0 == bd1 && bj0 < bj1);
    float bdA = p01 ? bd0 : bd1; int bjA = p01 ? bj0 : bj1;
    bool p23 = (bd2 < bd3) || (bd2 == bd3 && bj2 < bj3);
    float bdB = p23 ? bd2 : bd3; int bjB = p23 ? bj2 : bj3;
    bool pAB = (bdA < bdB) || (bdA == bdB && bjA < bjB);
    float bd = pAB ? bdA : bdB; int bj = pAB ? bjA : bjB;

    bool valid = sqrtf(fmaxf(bd, 0.f)) < 1.5f;

    int slab = slabtab[bj];
    if (valid && am != slab) atomicOr(&lbad[bj], 1);   // LDS atomic only
    iv_out[vox] = valid ? bj : -1;

    __syncthreads();
    // compact 512 flags -> 16 bitmap words; plain global stores (no atomics)
    if (tid < 16) {
        unsigned wd = 0;
        #pragma unroll
        for (int i = 0; i < 32; ++i)
            wd |= (lbad[tid * 32 + i] ? 1u : 0u) << i;
        bitmapT[tid * 1024 + B] = wd;
    }
}

// ------- reduce per-block bitmaps -> badw[16] -------
__global__ __launch_bounds__(256) void reduce_bad(const unsigned* __restrict__ bitmapT,
                                                  unsigned* __restrict__ badw) {
    __shared__ unsigned red[256];
    int w = blockIdx.x;      // word 0..15
    int tid = threadIdx.x;
    const unsigned* src = bitmapT + w * 1024;
    unsigned v = src[tid] | src[tid + 256] | src[tid + 512] | src[tid + 768];
    red[tid] = v;
    __syncthreads();
    #pragma unroll
    for (int s = 128; s > 0; s >>= 1) {
        if (tid < s) red[tid] |= red[tid + s];
        __syncthreads();
    }
    if (tid == 0) badw[w] = red[0];
}

// ---------------- finalize pseudo labels (bitmap test) ----------------
__global__ void finalize_kernel(const int* __restrict__ iv,
                                const unsigned* __restrict__ badw,
                                float* __restrict__ pl) {
    int t = blockIdx.x * 256 + threadIdx.x;
    if (t >= NVOX) return;
    int v = iv[t];
    float r = -1.0f;
    if (v >= 0 && !((badw[v >> 5] >> (v & 31)) & 1u)) r = (float)v;
    pl[t] = r;
}

extern "C" void kernel_launch(void* const* d_in, const int* in_sizes, int n_in,
                              void* d_out, int out_size, void* d_ws, size_t ws_size,
                              hipStream_t stream) {
    const float* points   = (const float*)d_in[0];
    const float* features = (const float*)d_in[1];
    const float* ann      = (const float*)d_in[2];
    const float* w1       = (const float*)d_in[3];
    const float* b1       = (const float*)d_in[4];
    const float* w2       = (const float*)d_in[5];
    const float* b2       = (const float*)d_in[6];
    const float* sem_w    = (const float*)d_in[7];
    const float* sem_b    = (const float*)d_in[8];
    const float* off_w    = (const float*)d_in[9];
    const float* off_b    = (const float*)d_in[10];

    float* out        = (float*)d_out;
    float* out_logits = out;
    float* out_off    = out + (size_t)NVOX * NCLS;   // N*20
    float* out_pl     = out + (size_t)NVOX * 23;     // N*23

    // workspace layout (bytes)
    char*  ws  = (char*)d_ws;
    float*          w1t     = (float*)         (ws);             //    41472 B
    unsigned*       badw    = (unsigned*)      (ws + 41472);     //       64 B
    unsigned short* bfr     = (unsigned short*)(ws + 43520);     //   110592 B (hi only)
    int*            iv      = (int*)           (ws + 264704);    //  1048576 B
    float*          seedtab = (float*)         (ws + 1313280);   //     8192 B
    int*            slabtab = (int*)           (ws + 1321472);   //     2048 B
    unsigned*       bitmapT = (unsigned*)      (ws + 1323520);   //    65536 B
    unsigned short* h1hi    = (unsigned short*)(ws + 34867712);  // 33554432 B

    transpose_w1<<<43, 256, 0, stream>>>(w1, w1t, ann, seedtab, slabtab);
    build_bfrags<<<27, 256, 0, stream>>>(w2, bfr);
    conv1_kernel<<<1024, 256, 0, stream>>>(features, w1t, b1, h1hi);
    conv2_fused_kernel<<<1024, 256, 0, stream>>>(h1hi, bfr, b2, seedtab, slabtab,
        points, sem_w, sem_b, off_w, off_b, out_logits, out_off, iv, bitmapT);
    reduce_bad<<<16, 256, 0, stream>>>(bitmapT, badw);
    finalize_kernel<<<1024, 256, 0, stream>>>(iv, badw, out_pl);
}